// Round 1
// baseline (2173.952 us; speedup 1.0000x reference)
//
#include <hip/hip_runtime.h>
#include <hip/hip_bf16.h>

#define B_   4
#define T_   2048
#define C_   1024
#define NH   16
#define HD   64

// ---------- bf16 helpers (bit tricks; avoid API surface uncertainty) ----------
__device__ __forceinline__ float bf2f(unsigned short h) {
    return __uint_as_float(((unsigned)h) << 16);
}
__device__ __forceinline__ unsigned short f2bf(float f) {
    unsigned u = __float_as_uint(f);
    unsigned r = (u + 0x7FFFu + ((u >> 16) & 1u)) >> 16;   // RNE
    return (unsigned short)r;
}

// =====================================================================
// Kernel 1: qkv = x @ w_qkv + b_qkv, scattered to Q/K/V [B,H,T,D] bf16
// grid: (3C/64, B*T/64) = (48, 128); block 256
// =====================================================================
__global__ __launch_bounds__(256) void qkv_gemm(
    const float* __restrict__ x,       // [8192,1024]
    const float* __restrict__ w,       // [1024,3072]
    const float* __restrict__ bias,    // [3072]
    unsigned short* __restrict__ qkv)  // 3 x [B,NH,T,HD] bf16, contiguous
{
    const int n0 = blockIdx.x * 64;
    const int m0 = blockIdx.y * 64;
    const int K = C_;
    const int N = 3 * C_;

    __shared__ float As[16][64];   // [kk][mi]
    __shared__ float Bs[16][64];   // [kk][nj]

    const int t  = threadIdx.x;
    const int tx = t & 15;         // 0..15  (cols)
    const int ty = t >> 4;         // 0..15  (rows)

    float acc[4][4] = {};

    for (int k0 = 0; k0 < K; k0 += 16) {
        // A tile: 64 rows x 16 k, float4 per thread
        {
            int mi = t >> 2;
            int f  = (t & 3) * 4;
            float4 a4 = *reinterpret_cast<const float4*>(&x[(size_t)(m0 + mi) * K + k0 + f]);
            As[f + 0][mi] = a4.x; As[f + 1][mi] = a4.y;
            As[f + 2][mi] = a4.z; As[f + 3][mi] = a4.w;
            int kk = t >> 4;
            int nj = (t & 15) * 4;
            float4 b4 = *reinterpret_cast<const float4*>(&w[(size_t)(k0 + kk) * N + n0 + nj]);
            *reinterpret_cast<float4*>(&Bs[kk][nj]) = b4;
        }
        __syncthreads();
#pragma unroll
        for (int kk = 0; kk < 16; ++kk) {
            float4 a = *reinterpret_cast<const float4*>(&As[kk][ty * 4]);
            float4 b = *reinterpret_cast<const float4*>(&Bs[kk][tx * 4]);
            const float* ap = (const float*)&a;
            const float* bp = (const float*)&b;
#pragma unroll
            for (int i = 0; i < 4; ++i)
#pragma unroll
                for (int j = 0; j < 4; ++j)
                    acc[i][j] += ap[i] * bp[j];
        }
        __syncthreads();
    }

    // epilogue: bias + scatter. Tile is 64-aligned so which/h/b are constant.
    const int which = n0 / C_;            // 0=Q 1=K 2=V
    const int c0    = n0 % C_;
    const int h     = c0 / HD;
    const int b     = m0 / T_;
    const int t0    = m0 % T_;
    unsigned short* dst = qkv + (size_t)which * (B_ * NH * T_ * HD);
#pragma unroll
    for (int i = 0; i < 4; ++i) {
        int row_t = t0 + ty * 4 + i;
        size_t base = (((size_t)(b * NH + h) * T_) + row_t) * HD + tx * 4;
#pragma unroll
        for (int j = 0; j < 4; ++j) {
            float v = acc[i][j] + bias[n0 + tx * 4 + j];
            dst[base + j] = f2bf(v);
        }
    }
}

// =====================================================================
// Kernel 2: flash attention per (b,h, 64-row q tile), causal.
// grid: (T/64, B*NH) = (32, 64); block 256
// Q,K,V bf16 [B,NH,T,HD]; Y bf16 [B,T,NH,HD]
// =====================================================================
__global__ __launch_bounds__(256) void attn(
    const unsigned short* __restrict__ Q,
    const unsigned short* __restrict__ K,
    const unsigned short* __restrict__ V,
    unsigned short* __restrict__ Y)
{
    const int qt = blockIdx.x;
    const int bh = blockIdx.y;
    const int q0 = qt * 64;
    const int b  = bh / NH, h = bh % NH;
    const size_t base = (size_t)bh * T_ * HD;

    __shared__ float Qs[64][68];    // [d][qi], pre-scaled by 1/8
    __shared__ float KsSt[64][68];  // phase A: K^T [d][kj]; phase B: P^T [kk][qi]
    __shared__ float Vs[64][64];    // [kk][d]
    __shared__ float mrow[64], lrow[64], alpha_s[64];

    const int t  = threadIdx.x;
    const int tx = t & 15;
    const int ty = t >> 4;

    float acc[4][4] = {};

    if (t < 64) { mrow[t] = -1e30f; lrow[t] = 0.f; }

    for (int idx = t; idx < 64 * 64; idx += 256) {
        int qi = idx >> 6, d = idx & 63;
        Qs[d][qi] = bf2f(Q[base + (size_t)(q0 + qi) * HD + d]) * 0.125f;
    }

    for (int kt = 0; kt <= qt; ++kt) {
        const int k0 = kt * 64;
        __syncthreads();   // protect KsSt/Vs from prior-iter readers; Qs/mrow on iter 0
        for (int idx = t; idx < 64 * 64; idx += 256) {
            int r = idx >> 6, d = idx & 63;
            KsSt[d][r] = bf2f(K[base + (size_t)(k0 + r) * HD + d]);
            Vs[r][d]   = bf2f(V[base + (size_t)(k0 + r) * HD + d]);
        }
        __syncthreads();

        // S = (Q*scale) K^T  -> registers
        float s[4][4] = {};
        for (int d = 0; d < 64; ++d) {
            float4 qv = *reinterpret_cast<const float4*>(&Qs[d][ty * 4]);
            float4 kv = *reinterpret_cast<const float4*>(&KsSt[d][tx * 4]);
            const float* qp = (const float*)&qv;
            const float* kp = (const float*)&kv;
#pragma unroll
            for (int i = 0; i < 4; ++i)
#pragma unroll
                for (int j = 0; j < 4; ++j)
                    s[i][j] += qp[i] * kp[j];
        }
        if (kt == qt) {   // causal mask on diagonal tile
#pragma unroll
            for (int i = 0; i < 4; ++i)
#pragma unroll
                for (int j = 0; j < 4; ++j)
                    if ((ty * 4 + i) < (tx * 4 + j)) s[i][j] = -1e30f;
        }
        __syncthreads();  // all reads of KsSt (as K^T) done
#pragma unroll
        for (int i = 0; i < 4; ++i)
#pragma unroll
            for (int j = 0; j < 4; ++j)
                KsSt[tx * 4 + j][ty * 4 + i] = s[i][j];   // store S^T
        __syncthreads();

        // online softmax, one thread per q row
        if (t < 64) {
            float mold = mrow[t];
            float mnew = mold;
#pragma unroll 8
            for (int kk = 0; kk < 64; ++kk) mnew = fmaxf(mnew, KsSt[kk][t]);
            float al = __expf(mold - mnew);
            float ls = 0.f;
#pragma unroll 8
            for (int kk = 0; kk < 64; ++kk) {
                float p = __expf(KsSt[kk][t] - mnew);
                KsSt[kk][t] = p;
                ls += p;
            }
            lrow[t]    = lrow[t] * al + ls;
            mrow[t]    = mnew;
            alpha_s[t] = al;
        }
        __syncthreads();

        // O = O*alpha + P V
#pragma unroll
        for (int i = 0; i < 4; ++i) {
            float al = alpha_s[ty * 4 + i];
#pragma unroll
            for (int j = 0; j < 4; ++j) acc[i][j] *= al;
        }
        for (int kk = 0; kk < 64; ++kk) {
            float4 pv = *reinterpret_cast<const float4*>(&KsSt[kk][ty * 4]);
            float4 vv = *reinterpret_cast<const float4*>(&Vs[kk][tx * 4]);
            const float* pp = (const float*)&pv;
            const float* vp = (const float*)&vv;
#pragma unroll
            for (int i = 0; i < 4; ++i)
#pragma unroll
                for (int j = 0; j < 4; ++j)
                    acc[i][j] += pp[i] * vp[j];
        }
    }

    // epilogue: Y[b, q, h, d] = O / l
#pragma unroll
    for (int i = 0; i < 4; ++i) {
        float inv = 1.f / lrow[ty * 4 + i];
        size_t o = (((size_t)(b * T_ + q0 + ty * 4 + i)) * NH + h) * HD + tx * 4;
#pragma unroll
        for (int j = 0; j < 4; ++j)
            Y[o + j] = f2bf(acc[i][j] * inv);
    }
}

// =====================================================================
// Kernel 3: out = Y @ w_proj + b_proj  (Y bf16, out fp32)
// grid: (C/64, B*T/64) = (16, 128); block 256
// =====================================================================
__global__ __launch_bounds__(256) void proj_gemm(
    const unsigned short* __restrict__ A,  // [8192,1024] bf16
    const float* __restrict__ w,           // [1024,1024]
    const float* __restrict__ bias,        // [1024]
    float* __restrict__ out)               // [8192,1024]
{
    const int n0 = blockIdx.x * 64;
    const int m0 = blockIdx.y * 64;
    const int K = C_;
    const int N = C_;

    __shared__ float As[16][64];
    __shared__ float Bs[16][64];

    const int t  = threadIdx.x;
    const int tx = t & 15;
    const int ty = t >> 4;

    float acc[4][4] = {};

    for (int k0 = 0; k0 < K; k0 += 16) {
        {
            int mi = t >> 2;
            int f  = (t & 3) * 4;
            ushort4 u = *reinterpret_cast<const ushort4*>(&A[(size_t)(m0 + mi) * K + k0 + f]);
            As[f + 0][mi] = bf2f(u.x); As[f + 1][mi] = bf2f(u.y);
            As[f + 2][mi] = bf2f(u.z); As[f + 3][mi] = bf2f(u.w);
            int kk = t >> 4;
            int nj = (t & 15) * 4;
            float4 b4 = *reinterpret_cast<const float4*>(&w[(size_t)(k0 + kk) * N + n0 + nj]);
            *reinterpret_cast<float4*>(&Bs[kk][nj]) = b4;
        }
        __syncthreads();
#pragma unroll
        for (int kk = 0; kk < 16; ++kk) {
            float4 a = *reinterpret_cast<const float4*>(&As[kk][ty * 4]);
            float4 b = *reinterpret_cast<const float4*>(&Bs[kk][tx * 4]);
            const float* ap = (const float*)&a;
            const float* bp = (const float*)&b;
#pragma unroll
            for (int i = 0; i < 4; ++i)
#pragma unroll
                for (int j = 0; j < 4; ++j)
                    acc[i][j] += ap[i] * bp[j];
        }
        __syncthreads();
    }

#pragma unroll
    for (int i = 0; i < 4; ++i) {
        float4 o;
        o.x = acc[i][0] + bias[n0 + tx * 4 + 0];
        o.y = acc[i][1] + bias[n0 + tx * 4 + 1];
        o.z = acc[i][2] + bias[n0 + tx * 4 + 2];
        o.w = acc[i][3] + bias[n0 + tx * 4 + 3];
        *reinterpret_cast<float4*>(&out[(size_t)(m0 + ty * 4 + i) * N + n0 + tx * 4]) = o;
    }
}

// =====================================================================
extern "C" void kernel_launch(void* const* d_in, const int* in_sizes, int n_in,
                              void* d_out, int out_size, void* d_ws, size_t ws_size,
                              hipStream_t stream) {
    const float* x      = (const float*)d_in[0];
    const float* w_qkv  = (const float*)d_in[1];
    const float* b_qkv  = (const float*)d_in[2];
    const float* w_proj = (const float*)d_in[3];
    const float* b_proj = (const float*)d_in[4];
    float* out = (float*)d_out;

    const size_t TENS = (size_t)B_ * NH * T_ * HD;   // 8,388,608 elems
    unsigned short* ws = (unsigned short*)d_ws;
    unsigned short* Qp = ws;                 // bf16 [B,NH,T,HD]
    unsigned short* Kp = ws + TENS;
    unsigned short* Vp = ws + 2 * TENS;
    unsigned short* Yp = ws + 3 * TENS;      // bf16 [B,T,NH,HD]

    qkv_gemm<<<dim3(48, 128), 256, 0, stream>>>(x, w_qkv, b_qkv, Qp);
    attn<<<dim3(32, 64), 256, 0, stream>>>(Qp, Kp, Vp, Yp);
    proj_gemm<<<dim3(16, 128), 256, 0, stream>>>(Yp, w_proj, b_proj, out);
}

// Round 2
// 447.937 us; speedup vs baseline: 4.8533x; 4.8533x over previous
//
#include <hip/hip_runtime.h>
#include <hip/hip_bf16.h>

#define B_   4
#define T_   2048
#define C_   1024
#define NH   16
#define HD   64

typedef unsigned short u16;
typedef short bf16x8 __attribute__((ext_vector_type(8)));   // 8 bf16 = 4 VGPR (guide-verified operand type)
typedef float f32x4  __attribute__((ext_vector_type(4)));

#define MFMA_BF16(a, b, c) __builtin_amdgcn_mfma_f32_16x16x32_bf16((a), (b), (c), 0, 0, 0)

// RNE fp32 -> bf16 (bit trick, no API surface risk)
__device__ __forceinline__ u16 f2bf(float f) {
    unsigned u = __float_as_uint(f);
    return (u16)((u + 0x7FFFu + ((u >> 16) & 1u)) >> 16);
}
__device__ __forceinline__ bf16x8 pack8(float4 f0, float4 f1) {
    bf16x8 r;
    r[0] = (short)f2bf(f0.x); r[1] = (short)f2bf(f0.y);
    r[2] = (short)f2bf(f0.z); r[3] = (short)f2bf(f0.w);
    r[4] = (short)f2bf(f1.x); r[5] = (short)f2bf(f1.y);
    r[6] = (short)f2bf(f1.z); r[7] = (short)f2bf(f1.w);
    return r;
}

// async 16B global -> LDS (DMA; LDS dest = wave-uniform base + lane*16)
__device__ __forceinline__ void gl2lds16(const void* g, void* l) {
    __builtin_amdgcn_global_load_lds(
        (const __attribute__((address_space(1))) void*)g,
        (__attribute__((address_space(3))) void*)l,
        16, 0, 0);
}

// =====================================================================
// transpose_w: src fp32 [R][C] -> dst bf16 [C][R]   (weights to B^T layout)
// grid (C/32, R/32), block (32,8)
// =====================================================================
__global__ __launch_bounds__(256) void transpose_w(
    const float* __restrict__ src, u16* __restrict__ dst, int R, int Ccols)
{
    __shared__ float tile[32][33];
    const int c0 = blockIdx.x * 32, r0 = blockIdx.y * 32;
    const int tx = threadIdx.x, ty = threadIdx.y;
#pragma unroll
    for (int i = 0; i < 4; ++i)
        tile[ty + 8 * i][tx] = src[(size_t)(r0 + ty + 8 * i) * Ccols + c0 + tx];
    __syncthreads();
#pragma unroll
    for (int i = 0; i < 4; ++i)
        dst[(size_t)(c0 + ty + 8 * i) * R + r0 + tx] = f2bf(tile[tx][ty + 8 * i]);
}

// =====================================================================
// qkv_gemm_mfma: C[8192,3072] = x[8192,1024](f32) * wqT[3072,1024]^T + b
// scatter -> Q(*0.125)/K: [B,NH,T,HD] bf16, V: [B,NH,T,HD] bf16
// grid (24, 64), block 256 (4 waves, 2x2 quadrants, 4x4 16x16 tiles each)
// =====================================================================
__global__ __launch_bounds__(256) void qkv_gemm_mfma(
    const float* __restrict__ x, const u16* __restrict__ wqT,
    const float* __restrict__ bqkv,
    u16* __restrict__ Qo, u16* __restrict__ Ko, u16* __restrict__ Vo)
{
    __shared__ __attribute__((aligned(16))) float As[128 * 32];  // fp32 A tile, chunk-swizzled
    __shared__ __attribute__((aligned(16))) u16   Bs[128 * 32];  // bf16 B^T tile

    const int t = threadIdx.x, lane = t & 63, w = t >> 6;
    const int n = lane & 15, quad = lane >> 4;
    const int wr = w >> 1, wc = w & 1;
    const int m0 = blockIdx.y * 128, n0 = blockIdx.x * 128;
    const int tmask = t & ~63;

    f32x4 acc[4][4] = {};

    for (int k0 = 0; k0 < 1024; k0 += 32) {
        __syncthreads();
        // A: 128 rows x 32 f32 = 1024 16B-chunks (8/row), XOR-swizzled slots
#pragma unroll
        for (int p = 0; p < 4; ++p) {
            int id = t + p * 256;
            int row = id >> 3, cs = id & 7, c = cs ^ (row & 7);
            gl2lds16(&x[(size_t)(m0 + row) * 1024 + k0 + c * 4], &As[(tmask + p * 256) * 4]);
        }
        // B: 128 rows x 32 bf16 = 512 chunks (4/row), unswizzled
#pragma unroll
        for (int p = 0; p < 2; ++p) {
            int id = t + p * 256;
            int row = id >> 2, c = id & 3;
            gl2lds16(&wqT[(size_t)(n0 + row) * 1024 + k0 + c * 8], &Bs[(tmask + p * 256) * 8]);
        }
        __syncthreads();

        bf16x8 a[4], b[4];
#pragma unroll
        for (int i = 0; i < 4; ++i) {
            int row = wr * 64 + i * 16 + n;
            int s0 = (quad * 2) ^ (n & 7);      // chunk slot (k = quad*8 .. +3)
            int s1 = s0 ^ 1;                    // (quad*2+1) ^ (n&7)
            float4 f0 = *reinterpret_cast<const float4*>(&As[row * 32 + s0 * 4]);
            float4 f1 = *reinterpret_cast<const float4*>(&As[row * 32 + s1 * 4]);
            a[i] = pack8(f0, f1);
        }
#pragma unroll
        for (int j = 0; j < 4; ++j) {
            int row = wc * 64 + j * 16 + n;
            b[j] = *reinterpret_cast<const bf16x8*>(&Bs[row * 32 + quad * 8]);
        }
#pragma unroll
        for (int i = 0; i < 4; ++i)
#pragma unroll
            for (int j = 0; j < 4; ++j)
                acc[i][j] = MFMA_BF16(a[i], b[j], acc[i][j]);
    }

    // epilogue: bias + scatter (wave quadrant = 64 cols = one head, one "which")
    const int colbase = n0 + wc * 64;
    const int which = colbase >> 10;
    const int h = (colbase & 1023) >> 6;
    u16* dst = (which == 0) ? Qo : ((which == 1) ? Ko : Vo);
    const float sc = (which == 0) ? 0.125f : 1.0f;   // fold 1/sqrt(HD) into Q
#pragma unroll
    for (int i = 0; i < 4; ++i) {
#pragma unroll
        for (int r = 0; r < 4; ++r) {
            int m = m0 + wr * 64 + i * 16 + quad * 4 + r;
            int bb = m >> 11, trow = m & 2047;
            size_t obase = (((size_t)(bb * NH + h)) * 2048 + trow) * 64;
#pragma unroll
            for (int j = 0; j < 4; ++j) {
                float v = acc[i][j][r] + bqkv[colbase + j * 16 + n];
                dst[obase + j * 16 + n] = f2bf(v * sc);
            }
        }
    }
}

// =====================================================================
// transpose_v: V [bh][2048][64] bf16 -> Vt [bh][64][2048] bf16
// grid (32, 64), block 256
// =====================================================================
__global__ __launch_bounds__(256) void transpose_v(
    const u16* __restrict__ V, u16* __restrict__ Vt)
{
    __shared__ u16 tile[64 * 82];   // pad 82: conflict-light scalar column reads
    const int bh = blockIdx.y, t0 = blockIdx.x * 64;
    const int t = threadIdx.x;
    const u16* src = V + (size_t)bh * 131072 + (size_t)t0 * 64;
    u16* dst = Vt + (size_t)bh * 131072 + t0;
#pragma unroll
    for (int p = 0; p < 2; ++p) {
        int id = t + p * 256;
        int row = id >> 3, seg = id & 7;
        ushort4 u0 = *reinterpret_cast<const ushort4*>(&src[row * 64 + seg * 8]);
        ushort4 u1 = *reinterpret_cast<const ushort4*>(&src[row * 64 + seg * 8 + 4]);
        u16* tp = &tile[row * 82 + seg * 8];
        tp[0] = u0.x; tp[1] = u0.y; tp[2] = u0.z; tp[3] = u0.w;
        tp[4] = u1.x; tp[5] = u1.y; tp[6] = u1.z; tp[7] = u1.w;
    }
    __syncthreads();
#pragma unroll
    for (int p = 0; p < 2; ++p) {
        int id = t + p * 256;
        int d = id >> 3, ks = id & 7;
        u16 u[8];
#pragma unroll
        for (int j = 0; j < 8; ++j) u[j] = tile[(ks * 8 + j) * 82 + d];
        *reinterpret_cast<ushort4*>(&dst[(size_t)d * 2048 + ks * 8])     = make_ushort4(u[0], u[1], u[2], u[3]);
        *reinterpret_cast<ushort4*>(&dst[(size_t)d * 2048 + ks * 8 + 4]) = make_ushort4(u[4], u[5], u[6], u[7]);
    }
}

// =====================================================================
// attn_mfma: flash attention, MFMA everywhere.
// block = 4 waves; wave w owns S/O rows [w*16, w*16+16) of a 64-row q-tile.
// grid (32, 64)   Q,K: [bh][t][d] (Q pre-scaled); Vt: [bh][d][t]; Y: [B,T,NH,HD]
// =====================================================================
__global__ __launch_bounds__(256) void attn_mfma(
    const u16* __restrict__ Q, const u16* __restrict__ K,
    const u16* __restrict__ Vt, u16* __restrict__ Y)
{
    const int qt = blockIdx.x, bh = blockIdx.y;
    const int q0 = qt * 64;
    const int b = bh >> 4, h = bh & 15;
    const size_t base = (size_t)bh * 131072;

    __shared__ __attribute__((aligned(16))) u16 Qs[64 * 64];   // [q][d], chunk-swizzled
    __shared__ __attribute__((aligned(16))) u16 Ks[64 * 64];   // [k][d], chunk-swizzled
    __shared__ __attribute__((aligned(16))) u16 Vs[64 * 64];   // [d][k], chunk-swizzled
    __shared__ __attribute__((aligned(16))) u16 Ps[4][16 * 72]; // per-wave P strip, pad 72

    const int t = threadIdx.x, lane = t & 63, w = t >> 6;
    const int n = lane & 15, quad = lane >> 4;
    const int tmask = t & ~63;

    // stage Q once (swizzled chunks so b128 frag reads are 8-way not 16-way)
#pragma unroll
    for (int p = 0; p < 2; ++p) {
        int id = t + p * 256;
        int row = id >> 3, cs = id & 7, c = cs ^ (row & 7);
        gl2lds16(&Q[base + (size_t)(q0 + row) * 64 + c * 8], &Qs[(tmask + p * 256) * 8]);
    }

    f32x4 o[4] = {};
    float mold[4], lrow[4];
#pragma unroll
    for (int r = 0; r < 4; ++r) { mold[r] = -1e30f; lrow[r] = 0.f; }
    bf16x8 qa[2];

    for (int kt = 0; kt <= qt; ++kt) {
        const int k0 = kt * 64;
        __syncthreads();   // prior-iter Ks/Vs readers done (and Q DMA complete on iter 0)
#pragma unroll
        for (int p = 0; p < 2; ++p) {
            int id = t + p * 256;
            int row = id >> 3, cs = id & 7, c = cs ^ (row & 7);
            gl2lds16(&K[base + (size_t)(k0 + row) * 64 + c * 8], &Ks[(tmask + p * 256) * 8]);
            gl2lds16(&Vt[base + (size_t)row * 2048 + k0 + c * 8], &Vs[(tmask + p * 256) * 8]);
        }
        __syncthreads();

        if (kt == 0) {   // Qs is ready and immutable; load A-frags once
            int row = w * 16 + n;
#pragma unroll
            for (int ks = 0; ks < 2; ++ks) {
                int slot = (quad + ks * 4) ^ (n & 7);
                qa[ks] = *reinterpret_cast<const bf16x8*>(&Qs[row * 64 + slot * 8]);
            }
        }

        // S = Q K^T  (wave strip 16 x 64 = 4 tiles)
        f32x4 s[4] = {};
#pragma unroll
        for (int nt = 0; nt < 4; ++nt) {
            int row = nt * 16 + n;
#pragma unroll
            for (int ks = 0; ks < 2; ++ks) {
                int slot = (quad + ks * 4) ^ (n & 7);
                bf16x8 kb = *reinterpret_cast<const bf16x8*>(&Ks[row * 64 + slot * 8]);
                s[nt] = MFMA_BF16(qa[ks], kb, s[nt]);
            }
        }

        if (kt == qt) {  // causal mask on diagonal tile (q0 == k0)
#pragma unroll
            for (int nt = 0; nt < 4; ++nt)
#pragma unroll
                for (int r = 0; r < 4; ++r)
                    if (nt * 16 + n > w * 16 + quad * 4 + r) s[nt][r] = -1e30f;
        }

        // online softmax: row (w*16+quad*4+r) lives in this quad's 16 lanes
        float alpha[4], p_[4][4];
#pragma unroll
        for (int r = 0; r < 4; ++r) {
            float mx = fmaxf(fmaxf(s[0][r], s[1][r]), fmaxf(s[2][r], s[3][r]));
            mx = fmaxf(mx, __shfl_xor(mx, 1, 64));
            mx = fmaxf(mx, __shfl_xor(mx, 2, 64));
            mx = fmaxf(mx, __shfl_xor(mx, 4, 64));
            mx = fmaxf(mx, __shfl_xor(mx, 8, 64));
            float mnew = fmaxf(mold[r], mx);
            alpha[r] = __expf(mold[r] - mnew);
            float rs = 0.f;
#pragma unroll
            for (int nt = 0; nt < 4; ++nt) {
                float pv = __expf(s[nt][r] - mnew);
                p_[nt][r] = pv; rs += pv;
            }
            rs += __shfl_xor(rs, 1, 64);
            rs += __shfl_xor(rs, 2, 64);
            rs += __shfl_xor(rs, 4, 64);
            rs += __shfl_xor(rs, 8, 64);
            lrow[r] = lrow[r] * alpha[r] + rs;
            mold[r] = mnew;
        }

        // P: C-layout regs -> A-layout via wave-private LDS strip (m120 transform)
        u16* myPs = Ps[w];
#pragma unroll
        for (int nt = 0; nt < 4; ++nt)
#pragma unroll
            for (int r = 0; r < 4; ++r)
                myPs[(quad * 4 + r) * 72 + nt * 16 + n] = f2bf(p_[nt][r]);

#pragma unroll
        for (int dt = 0; dt < 4; ++dt)
#pragma unroll
            for (int r = 0; r < 4; ++r) o[dt][r] *= alpha[r];

        // O += P V   (A-frags from Ps, B-frags contiguous from Vs=[d][k])
        bf16x8 pa[2];
#pragma unroll
        for (int ks = 0; ks < 2; ++ks)
            pa[ks] = *reinterpret_cast<const bf16x8*>(&myPs[n * 72 + ks * 32 + quad * 8]);
#pragma unroll
        for (int dt = 0; dt < 4; ++dt) {
            int row = dt * 16 + n;
#pragma unroll
            for (int ks = 0; ks < 2; ++ks) {
                int slot = (quad + ks * 4) ^ (n & 7);
                bf16x8 vb = *reinterpret_cast<const bf16x8*>(&Vs[row * 64 + slot * 8]);
                o[dt] = MFMA_BF16(pa[ks], vb, o[dt]);
            }
        }
    }

    // epilogue: Y[b, q, h, d] = O / l
#pragma unroll
    for (int r = 0; r < 4; ++r) {
        float inv = 1.f / lrow[r];
        int q = q0 + w * 16 + quad * 4 + r;
        size_t ob = (((size_t)(b * 2048 + q)) * NH + h) * 64;
#pragma unroll
        for (int dt = 0; dt < 4; ++dt)
            Y[ob + dt * 16 + n] = f2bf(o[dt][r] * inv);
    }
}

// =====================================================================
// proj_gemm_mfma: out[8192,1024] f32 = Y[8192,1024](bf16) * wpT[1024,1024]^T + b
// grid (8, 64), block 256
// =====================================================================
__global__ __launch_bounds__(256) void proj_gemm_mfma(
    const u16* __restrict__ A, const u16* __restrict__ BT,
    const float* __restrict__ bias, float* __restrict__ out)
{
    __shared__ __attribute__((aligned(16))) u16 As[128 * 32];
    __shared__ __attribute__((aligned(16))) u16 Bs[128 * 32];

    const int t = threadIdx.x, lane = t & 63, w = t >> 6;
    const int n = lane & 15, quad = lane >> 4;
    const int wr = w >> 1, wc = w & 1;
    const int m0 = blockIdx.y * 128, n0 = blockIdx.x * 128;
    const int tmask = t & ~63;

    f32x4 acc[4][4] = {};

    for (int k0 = 0; k0 < 1024; k0 += 32) {
        __syncthreads();
#pragma unroll
        for (int p = 0; p < 2; ++p) {
            int id = t + p * 256;
            int row = id >> 2, c = id & 3;
            gl2lds16(&A[(size_t)(m0 + row) * 1024 + k0 + c * 8], &As[(tmask + p * 256) * 8]);
            gl2lds16(&BT[(size_t)(n0 + row) * 1024 + k0 + c * 8], &Bs[(tmask + p * 256) * 8]);
        }
        __syncthreads();

        bf16x8 a[4], b[4];
#pragma unroll
        for (int i = 0; i < 4; ++i)
            a[i] = *reinterpret_cast<const bf16x8*>(&As[(wr * 64 + i * 16 + n) * 32 + quad * 8]);
#pragma unroll
        for (int j = 0; j < 4; ++j)
            b[j] = *reinterpret_cast<const bf16x8*>(&Bs[(wc * 64 + j * 16 + n) * 32 + quad * 8]);
#pragma unroll
        for (int i = 0; i < 4; ++i)
#pragma unroll
            for (int j = 0; j < 4; ++j)
                acc[i][j] = MFMA_BF16(a[i], b[j], acc[i][j]);
    }

#pragma unroll
    for (int i = 0; i < 4; ++i)
#pragma unroll
        for (int r = 0; r < 4; ++r) {
            int m = m0 + wr * 64 + i * 16 + quad * 4 + r;
#pragma unroll
            for (int j = 0; j < 4; ++j) {
                int col = n0 + wc * 64 + j * 16 + n;
                out[(size_t)m * 1024 + col] = acc[i][j][r] + bias[col];
            }
        }
}

// =====================================================================
// Workspace overlay (64 MB total — proven available in round 1):
//   [0,16M):  Q            ... later wpT (after attn)
//   [16,32M): K
//   [32,48M): V            ... later Y (after transpose_v)
//   [48,64M): wqT (6MB)    ... later Vt (after qkv_gemm)
// =====================================================================
extern "C" void kernel_launch(void* const* d_in, const int* in_sizes, int n_in,
                              void* d_out, int out_size, void* d_ws, size_t ws_size,
                              hipStream_t stream) {
    const float* x      = (const float*)d_in[0];
    const float* w_qkv  = (const float*)d_in[1];
    const float* b_qkv  = (const float*)d_in[2];
    const float* w_proj = (const float*)d_in[3];
    const float* b_proj = (const float*)d_in[4];
    float* out = (float*)d_out;

    const size_t E16 = 8388608;            // elements per 16 MB bf16 tensor
    u16* ws  = (u16*)d_ws;
    u16* Qp  = ws;                         // 0
    u16* Kp  = ws + E16;                   // 16 MB
    u16* Vp  = ws + 2 * E16;               // 32 MB
    u16* wqT = ws + 3 * E16;               // 48 MB (uses 6 MB)
    u16* VtP = ws + 3 * E16;               // 48 MB (over dead wqT)
    u16* Yp  = ws + 2 * E16;               // 32 MB (over dead V)
    u16* wpT = ws;                         // 0    (over dead Q)

    transpose_w<<<dim3(96, 32), dim3(32, 8), 0, stream>>>(w_qkv, wqT, 1024, 3072);
    qkv_gemm_mfma<<<dim3(24, 64), 256, 0, stream>>>(x, wqT, b_qkv, Qp, Kp, Vp);
    transpose_v<<<dim3(32, 64), 256, 0, stream>>>(Vp, VtP);
    attn_mfma<<<dim3(32, 64), 256, 0, stream>>>(Qp, Kp, VtP, Yp);
    transpose_w<<<dim3(32, 32), dim3(32, 8), 0, stream>>>(w_proj, wpT, 1024, 1024);
    proj_gemm_mfma<<<dim3(8, 64), 256, 0, stream>>>(Yp, wpT, b_proj, out);
}

// Round 4
// 322.130 us; speedup vs baseline: 6.7487x; 1.3905x over previous
//
#include <hip/hip_runtime.h>
#include <hip/hip_bf16.h>

#define B_   4
#define T_   2048
#define C_   1024
#define NH   16
#define HD   64

typedef unsigned short u16;
typedef short bf16x8 __attribute__((ext_vector_type(8)));   // 8 bf16 = 4 VGPR
typedef short bf16x4 __attribute__((ext_vector_type(4)));   // 4 bf16 = 2 VGPR
typedef float f32x4  __attribute__((ext_vector_type(4)));

#define MFMA_BF16(a, b, c) __builtin_amdgcn_mfma_f32_16x16x32_bf16((a), (b), (c), 0, 0, 0)

__device__ __forceinline__ u16 f2bf(float f) {
    unsigned u = __float_as_uint(f);
    return (u16)((u + 0x7FFFu + ((u >> 16) & 1u)) >> 16);   // RNE
}
__device__ __forceinline__ bf16x8 pack8(float4 f0, float4 f1) {
    bf16x8 r;
    r[0] = (short)f2bf(f0.x); r[1] = (short)f2bf(f0.y);
    r[2] = (short)f2bf(f0.z); r[3] = (short)f2bf(f0.w);
    r[4] = (short)f2bf(f1.x); r[5] = (short)f2bf(f1.y);
    r[6] = (short)f2bf(f1.z); r[7] = (short)f2bf(f1.w);
    return r;
}
__device__ __forceinline__ bf16x4 pack4(f32x4 v) {
    bf16x4 r;
    r[0] = (short)f2bf(v[0]); r[1] = (short)f2bf(v[1]);
    r[2] = (short)f2bf(v[2]); r[3] = (short)f2bf(v[3]);
    return r;
}

// async 16B global -> LDS (DMA; LDS dest = wave-uniform base + lane*16)
__device__ __forceinline__ void gl2lds16(const void* g, void* l) {
    __builtin_amdgcn_global_load_lds(
        (const __attribute__((address_space(1))) void*)g,
        (__attribute__((address_space(3))) void*)l,
        16, 0, 0);
}

// =====================================================================
// cast_x: fp32 [8192*1024] -> bf16 (one bf16x8 store / thread-iter)
// grid 4096, block 256  (4096*256*8 == 8388608 exactly)
// =====================================================================
__global__ __launch_bounds__(256) void cast_x(
    const float* __restrict__ x, u16* __restrict__ xb)
{
    int i = (blockIdx.x * 256 + threadIdx.x) * 8;
    float4 f0 = *reinterpret_cast<const float4*>(&x[i]);
    float4 f1 = *reinterpret_cast<const float4*>(&x[i + 4]);
    *reinterpret_cast<bf16x8*>(&xb[i]) = pack8(f0, f1);
}

// =====================================================================
// transpose_w: src fp32 [R][C] -> dst bf16 [C][R]   (weights to B^T layout)
// =====================================================================
__global__ __launch_bounds__(256) void transpose_w(
    const float* __restrict__ src, u16* __restrict__ dst, int R, int Ccols)
{
    __shared__ float tile[32][33];
    const int c0 = blockIdx.x * 32, r0 = blockIdx.y * 32;
    const int tx = threadIdx.x, ty = threadIdx.y;
#pragma unroll
    for (int i = 0; i < 4; ++i)
        tile[ty + 8 * i][tx] = src[(size_t)(r0 + ty + 8 * i) * Ccols + c0 + tx];
    __syncthreads();
#pragma unroll
    for (int i = 0; i < 4; ++i)
        dst[(size_t)(c0 + ty + 8 * i) * R + r0 + tx] = f2bf(tile[tx][ty + 8 * i]);
}

// =====================================================================
// qkv_gemm_mfma: pure-bf16 m97-style. C[8192,3072] = xb * wqT^T + b
// scatter -> Q(*0.125)/K/V [B,NH,T,HD] bf16. grid (24,64), block 256.
// BK=32, XOR chunk swizzle (^row&3) for conflict-light b128 frag reads.
// =====================================================================
__global__ __launch_bounds__(256, 3) void qkv_gemm_mfma(
    const u16* __restrict__ xb, const u16* __restrict__ wqT,
    const float* __restrict__ bqkv,
    u16* __restrict__ Qo, u16* __restrict__ Ko, u16* __restrict__ Vo)
{
    __shared__ __attribute__((aligned(16))) u16 As[128 * 32];
    __shared__ __attribute__((aligned(16))) u16 Bs[128 * 32];

    const int t = threadIdx.x, lane = t & 63, w = t >> 6;
    const int n = lane & 15, quad = lane >> 4;
    const int wr = w >> 1, wc = w & 1;
    const int m0 = blockIdx.y * 128, n0 = blockIdx.x * 128;
    const int tmask = t & ~63;

    f32x4 acc[4][4] = {};

    for (int k0 = 0; k0 < 1024; k0 += 32) {
        __syncthreads();
#pragma unroll
        for (int p = 0; p < 2; ++p) {
            int id = t + p * 256;
            int row = id >> 2, c = (id & 3) ^ (row & 3);
            gl2lds16(&xb[(size_t)(m0 + row) * 1024 + k0 + c * 8], &As[(tmask + p * 256) * 8]);
            gl2lds16(&wqT[(size_t)(n0 + row) * 1024 + k0 + c * 8], &Bs[(tmask + p * 256) * 8]);
        }
        __syncthreads();

        const int slot = (quad ^ (n & 3)) * 8;
        bf16x8 a[4], b[4];
#pragma unroll
        for (int i = 0; i < 4; ++i)
            a[i] = *reinterpret_cast<const bf16x8*>(&As[(wr * 64 + i * 16 + n) * 32 + slot]);
#pragma unroll
        for (int j = 0; j < 4; ++j)
            b[j] = *reinterpret_cast<const bf16x8*>(&Bs[(wc * 64 + j * 16 + n) * 32 + slot]);
#pragma unroll
        for (int i = 0; i < 4; ++i)
#pragma unroll
            for (int j = 0; j < 4; ++j)
                acc[i][j] = MFMA_BF16(a[i], b[j], acc[i][j]);
    }

    // epilogue: bias + scatter (wave half = 64 cols = one head, one "which")
    const int colbase = n0 + wc * 64;
    const int which = colbase >> 10;
    const int h = (colbase & 1023) >> 6;
    u16* dst = (which == 0) ? Qo : ((which == 1) ? Ko : Vo);
    const float sc = (which == 0) ? 0.125f : 1.0f;   // fold 1/sqrt(HD) into Q
#pragma unroll
    for (int i = 0; i < 4; ++i) {
#pragma unroll
        for (int r = 0; r < 4; ++r) {
            int m = m0 + wr * 64 + i * 16 + quad * 4 + r;
            int bb = m >> 11, trow = m & 2047;
            size_t obase = (((size_t)(bb * NH + h)) * 2048 + trow) * 64;
#pragma unroll
            for (int j = 0; j < 4; ++j) {
                float v = acc[i][j][r] + bqkv[colbase + j * 16 + n];
                dst[obase + j * 16 + n] = f2bf(v * sc);
            }
        }
    }
}

// =====================================================================
// transpose_v: V [bh][2048][64] bf16 -> Vt [bh][64][2048] bf16
// =====================================================================
__global__ __launch_bounds__(256) void transpose_v(
    const u16* __restrict__ V, u16* __restrict__ Vt)
{
    __shared__ u16 tile[64 * 82];
    const int bh = blockIdx.y, t0 = blockIdx.x * 64;
    const int t = threadIdx.x;
    const u16* src = V + (size_t)bh * 131072 + (size_t)t0 * 64;
    u16* dst = Vt + (size_t)bh * 131072 + t0;
#pragma unroll
    for (int p = 0; p < 2; ++p) {
        int id = t + p * 256;
        int row = id >> 3, seg = id & 7;
        ushort4 u0 = *reinterpret_cast<const ushort4*>(&src[row * 64 + seg * 8]);
        ushort4 u1 = *reinterpret_cast<const ushort4*>(&src[row * 64 + seg * 8 + 4]);
        u16* tp = &tile[row * 82 + seg * 8];
        tp[0] = u0.x; tp[1] = u0.y; tp[2] = u0.z; tp[3] = u0.w;
        tp[4] = u1.x; tp[5] = u1.y; tp[6] = u1.z; tp[7] = u1.w;
    }
    __syncthreads();
#pragma unroll
    for (int p = 0; p < 2; ++p) {
        int id = t + p * 256;
        int d = id >> 3, ks = id & 7;
        u16 u[8];
#pragma unroll
        for (int j = 0; j < 8; ++j) u[j] = tile[(ks * 8 + j) * 82 + d];
        *reinterpret_cast<ushort4*>(&dst[(size_t)d * 2048 + ks * 8])     = make_ushort4(u[0], u[1], u[2], u[3]);
        *reinterpret_cast<ushort4*>(&dst[(size_t)d * 2048 + ks * 8 + 4]) = make_ushort4(u[4], u[5], u[6], u[7]);
    }
}

// =====================================================================
// attn_mfma v2: S^T formulation -> lane-local softmax.
//   S^T = K Q^T  (A=K tile, B=Q tile) -> C col = q = lane&15
//   O^T = V^T P^T (A=V^T, B=P^T)      -> C col = q, row = d
// Block: 128 q rows (4 waves x 32 q), k-tile 64. grid (16, 64).
// Waves skip fully-masked k-tiles; qt dispatched descending (long first).
// =====================================================================
__global__ __launch_bounds__(256, 3) void attn_mfma(
    const u16* __restrict__ Q, const u16* __restrict__ K,
    const u16* __restrict__ Vt, u16* __restrict__ Y)
{
    const int qt = (int)gridDim.x - 1 - (int)blockIdx.x;   // longest blocks first
    const int bh = blockIdx.y;
    const int q0 = qt * 128;
    const int b = bh >> 4, h = bh & 15;
    const size_t base = (size_t)bh * (T_ * HD);

    __shared__ __attribute__((aligned(16))) u16 Qs[128 * 64];  // [q][d] swizzled
    __shared__ __attribute__((aligned(16))) u16 Ks[64 * 64];   // [k][d] swizzled
    __shared__ __attribute__((aligned(16))) u16 Vs[64 * 64];   // [d][k] swizzled
    __shared__ __attribute__((aligned(16))) u16 Ps[4][32 * 72]; // per-wave P^T strip [q][k], stride 72 (16B-aligned rows)

    const int t = threadIdx.x, lane = t & 63, w = t >> 6;
    const int n = lane & 15, quad = lane >> 4;
    const int tmask = t & ~63;
    const int qw_lo = q0 + w * 32;         // first q row this wave owns
    const int qw_hi = qw_lo + 31;          // last q row this wave owns

    // stage Q once (1024 chunks)
#pragma unroll
    for (int p = 0; p < 4; ++p) {
        int id = t + p * 256;
        int row = id >> 3, c = (id & 7) ^ (row & 7);
        gl2lds16(&Q[base + (size_t)(q0 + row) * 64 + c * 8], &Qs[(tmask + p * 256) * 8]);
    }

    f32x4 o[2][4] = {};
    float mst[2] = {-1e30f, -1e30f}, lst[2] = {0.f, 0.f};
    bf16x8 qa[2][2];

    const int nkt = 2 * qt + 2;
    for (int kt = 0; kt < nkt; ++kt) {
        const int k0 = kt * 64;
        __syncthreads();   // prior-iter Ks/Vs readers done
#pragma unroll
        for (int p = 0; p < 2; ++p) {
            int id = t + p * 256;
            int row = id >> 3, c = (id & 7) ^ (row & 7);
            gl2lds16(&K[base + (size_t)(k0 + row) * 64 + c * 8], &Ks[(tmask + p * 256) * 8]);
            gl2lds16(&Vt[base + (size_t)row * 2048 + k0 + c * 8], &Vs[(tmask + p * 256) * 8]);
        }
        __syncthreads();   // staging (and on kt==0, Q DMA) complete

        if (kt == 0) {     // Qs immutable after this point; load B-frags once
#pragma unroll
            for (int nt2 = 0; nt2 < 2; ++nt2)
#pragma unroll
                for (int dh = 0; dh < 2; ++dh) {
                    int row = w * 32 + nt2 * 16 + n;
                    int slot = (quad + dh * 4) ^ (n & 7);
                    qa[nt2][dh] = *reinterpret_cast<const bf16x8*>(&Qs[row * 64 + slot * 8]);
                }
        }

        if (k0 > qw_hi) continue;   // fully masked for this wave (barriers already done)

        // ---- S^T = K Q^T : strip [64 k][32 q] ----
        bf16x8 kf[4][2];
#pragma unroll
        for (int mt = 0; mt < 4; ++mt)
#pragma unroll
            for (int dh = 0; dh < 2; ++dh) {
                int row = mt * 16 + n;
                int slot = (quad + dh * 4) ^ (n & 7);
                kf[mt][dh] = *reinterpret_cast<const bf16x8*>(&Ks[row * 64 + slot * 8]);
            }
        f32x4 s2[2][4] = {};
#pragma unroll
        for (int nt2 = 0; nt2 < 2; ++nt2)
#pragma unroll
            for (int mt = 0; mt < 4; ++mt)
#pragma unroll
                for (int dh = 0; dh < 2; ++dh)
                    s2[nt2][mt] = MFMA_BF16(kf[mt][dh], qa[nt2][dh], s2[nt2][mt]);

        // causal mask — needed whenever the tile's max k exceeds the wave's
        // LOWEST q (diagonal straddles different k-tiles per wave).
        // Round-3 bug: compared against qw_hi, leaking future tokens for waves 1-3.
        if (k0 + 63 > qw_lo) {
#pragma unroll
            for (int nt2 = 0; nt2 < 2; ++nt2) {
                int qrel = (qw_lo + nt2 * 16 + n) - k0;   // q - k0
#pragma unroll
                for (int mt = 0; mt < 4; ++mt)
#pragma unroll
                    for (int r = 0; r < 4; ++r)
                        if (mt * 16 + quad * 4 + r > qrel) s2[nt2][mt][r] = -1e30f;
            }
        }

        // ---- lane-local online softmax (lane owns q = nt2*16 + n) ----
        float alpha[2];
#pragma unroll
        for (int nt2 = 0; nt2 < 2; ++nt2) {
            float mx = -1e30f;
#pragma unroll
            for (int mt = 0; mt < 4; ++mt) {
                mx = fmaxf(mx, fmaxf(fmaxf(s2[nt2][mt][0], s2[nt2][mt][1]),
                                     fmaxf(s2[nt2][mt][2], s2[nt2][mt][3])));
            }
            mx = fmaxf(mx, __shfl_xor(mx, 16, 64));
            mx = fmaxf(mx, __shfl_xor(mx, 32, 64));
            float mnew = fmaxf(mst[nt2], mx);
            alpha[nt2] = __expf(mst[nt2] - mnew);
            float rs = 0.f;
#pragma unroll
            for (int mt = 0; mt < 4; ++mt) {
#pragma unroll
                for (int r = 0; r < 4; ++r) {
                    float p = __expf(s2[nt2][mt][r] - mnew);
                    s2[nt2][mt][r] = p;
                    rs += p;
                }
            }
            rs += __shfl_xor(rs, 16, 64);
            rs += __shfl_xor(rs, 32, 64);
            lst[nt2] = lst[nt2] * alpha[nt2] + rs;
            mst[nt2] = mnew;
        }

        // ---- P^T -> wave-private LDS strip (packed b64 writes) ----
        u16* myPs = Ps[w];
#pragma unroll
        for (int nt2 = 0; nt2 < 2; ++nt2)
#pragma unroll
            for (int mt = 0; mt < 4; ++mt)
                *reinterpret_cast<bf16x4*>(&myPs[(nt2 * 16 + n) * 72 + mt * 16 + quad * 4]) =
                    pack4(s2[nt2][mt]);

        // ---- rescale O, then O^T += V^T P^T ----
#pragma unroll
        for (int nt2 = 0; nt2 < 2; ++nt2)
#pragma unroll
            for (int dt = 0; dt < 4; ++dt)
                o[nt2][dt] *= alpha[nt2];

        bf16x8 pf[2][2];
#pragma unroll
        for (int nt2 = 0; nt2 < 2; ++nt2)
#pragma unroll
            for (int kh = 0; kh < 2; ++kh)
                pf[nt2][kh] = *reinterpret_cast<const bf16x8*>(
                    &myPs[(nt2 * 16 + n) * 72 + kh * 32 + quad * 8]);
        bf16x8 vf[4][2];
#pragma unroll
        for (int dt = 0; dt < 4; ++dt)
#pragma unroll
            for (int kh = 0; kh < 2; ++kh) {
                int row = dt * 16 + n;
                int slot = (quad + kh * 4) ^ (n & 7);
                vf[dt][kh] = *reinterpret_cast<const bf16x8*>(&Vs[row * 64 + slot * 8]);
            }
#pragma unroll
        for (int nt2 = 0; nt2 < 2; ++nt2)
#pragma unroll
            for (int dt = 0; dt < 4; ++dt)
#pragma unroll
                for (int kh = 0; kh < 2; ++kh)
                    o[nt2][dt] = MFMA_BF16(vf[dt][kh], pf[nt2][kh], o[nt2][dt]);
    }

    // epilogue: Y[b,q,h,d] = O^T / l   (lane q, d = dt*16+quad*4+r packed)
#pragma unroll
    for (int nt2 = 0; nt2 < 2; ++nt2) {
        float inv = 1.f / lst[nt2];
        int qg = qw_lo + nt2 * 16 + n;
        size_t ob = (((size_t)(b * 2048 + qg)) * NH + h) * 64;
#pragma unroll
        for (int dt = 0; dt < 4; ++dt) {
            ushort4 st = make_ushort4(f2bf(o[nt2][dt][0] * inv), f2bf(o[nt2][dt][1] * inv),
                                      f2bf(o[nt2][dt][2] * inv), f2bf(o[nt2][dt][3] * inv));
            *reinterpret_cast<ushort4*>(&Y[ob + dt * 16 + quad * 4]) = st;
        }
    }
}

// =====================================================================
// proj_gemm_mfma: out[8192,1024] f32 = Y(bf16) * wpT^T + b. grid (8,64).
// =====================================================================
__global__ __launch_bounds__(256, 3) void proj_gemm_mfma(
    const u16* __restrict__ A, const u16* __restrict__ BT,
    const float* __restrict__ bias, float* __restrict__ out)
{
    __shared__ __attribute__((aligned(16))) u16 As[128 * 32];
    __shared__ __attribute__((aligned(16))) u16 Bs[128 * 32];

    const int t = threadIdx.x, lane = t & 63, w = t >> 6;
    const int n = lane & 15, quad = lane >> 4;
    const int wr = w >> 1, wc = w & 1;
    const int m0 = blockIdx.y * 128, n0 = blockIdx.x * 128;
    const int tmask = t & ~63;

    f32x4 acc[4][4] = {};

    for (int k0 = 0; k0 < 1024; k0 += 32) {
        __syncthreads();
#pragma unroll
        for (int p = 0; p < 2; ++p) {
            int id = t + p * 256;
            int row = id >> 2, c = (id & 3) ^ (row & 3);
            gl2lds16(&A[(size_t)(m0 + row) * 1024 + k0 + c * 8], &As[(tmask + p * 256) * 8]);
            gl2lds16(&BT[(size_t)(n0 + row) * 1024 + k0 + c * 8], &Bs[(tmask + p * 256) * 8]);
        }
        __syncthreads();

        const int slot = (quad ^ (n & 3)) * 8;
        bf16x8 a[4], b[4];
#pragma unroll
        for (int i = 0; i < 4; ++i)
            a[i] = *reinterpret_cast<const bf16x8*>(&As[(wr * 64 + i * 16 + n) * 32 + slot]);
#pragma unroll
        for (int j = 0; j < 4; ++j)
            b[j] = *reinterpret_cast<const bf16x8*>(&Bs[(wc * 64 + j * 16 + n) * 32 + slot]);
#pragma unroll
        for (int i = 0; i < 4; ++i)
#pragma unroll
            for (int j = 0; j < 4; ++j)
                acc[i][j] = MFMA_BF16(a[i], b[j], acc[i][j]);
    }

#pragma unroll
    for (int i = 0; i < 4; ++i)
#pragma unroll
        for (int r = 0; r < 4; ++r) {
            int m = m0 + wr * 64 + i * 16 + quad * 4 + r;
#pragma unroll
            for (int j = 0; j < 4; ++j) {
                int col = n0 + wc * 64 + j * 16 + n;
                out[(size_t)m * 1024 + col] = acc[i][j][r] + bias[col];
            }
        }
}

// =====================================================================
// Workspace overlay (<= 64 MB ws + d_out used as pre-proj scratch):
//   ws [0,16M): Q      ... later wpT (after attn)
//   ws [16,32M): K
//   ws [32,48M): V     ... later Y (after transpose_v)
//   ws [48,54M): wqT   ... [48,64M): Vt (after qkv)
//   d_out [0,16M): xb (bf16 x) — dead before proj writes d_out
// =====================================================================
extern "C" void kernel_launch(void* const* d_in, const int* in_sizes, int n_in,
                              void* d_out, int out_size, void* d_ws, size_t ws_size,
                              hipStream_t stream) {
    const float* x      = (const float*)d_in[0];
    const float* w_qkv  = (const float*)d_in[1];
    const float* b_qkv  = (const float*)d_in[2];
    const float* w_proj = (const float*)d_in[3];
    const float* b_proj = (const float*)d_in[4];
    float* out = (float*)d_out;

    const size_t E16 = 8388608;
    u16* ws  = (u16*)d_ws;
    u16* Qp  = ws;
    u16* Kp  = ws + E16;
    u16* Vp  = ws + 2 * E16;
    u16* wqT = ws + 3 * E16;
    u16* VtP = ws + 3 * E16;
    u16* Yp  = ws + 2 * E16;
    u16* wpT = ws;
    u16* xb  = (u16*)d_out;                // scratch inside d_out, dead before proj

    cast_x<<<dim3(4096), 256, 0, stream>>>(x, xb);
    transpose_w<<<dim3(96, 32), dim3(32, 8), 0, stream>>>(w_qkv, wqT, 1024, 3072);
    qkv_gemm_mfma<<<dim3(24, 64), 256, 0, stream>>>(xb, wqT, b_qkv, Qp, Kp, Vp);
    transpose_v<<<dim3(32, 64), 256, 0, stream>>>(Vp, VtP);
    attn_mfma<<<dim3(16, 64), 256, 0, stream>>>(Qp, Kp, VtP, Yp);
    transpose_w<<<dim3(32, 32), dim3(32, 8), 0, stream>>>(w_proj, wpT, 1024, 1024);
    proj_gemm_mfma<<<dim3(8, 64), 256, 0, stream>>>(Yp, wpT, b_proj, out);
}